// Round 1
// baseline (85.490 us; speedup 1.0000x reference)
//
#include <hip/hip_runtime.h>

// y[b,o] = sum_i x[b,i] * (wp[i,o] - wn[i,o]) + (bp[o] - bn[o])
// (G_OFF / k_cond / K_V cancel exactly in the differential-pair readout)

#define NB   128
#define NIN  1024
#define NOUT 1024

#define BM   64      // batch rows per block
#define BN   32      // output cols per block
#define KC   128     // k-chunk per block (K split x8 across blocks)
#define XPAD 132     // xs row stride in floats (pad 128->132 keeps 16B align, breaks bank aliasing)

__global__ __launch_bounds__(256, 2) void memr_fc(
    const float* __restrict__ x,  const float* __restrict__ wp,
    const float* __restrict__ wn, const float* __restrict__ bp,
    const float* __restrict__ bn, float* __restrict__ out)
{
    __shared__ float xs[BM * XPAD];   // x chunk   [b][k]  33792 B
    __shared__ float wd[KC * BN];     // wp-wn     [k][o]  16384 B

    const int t  = threadIdx.x;
    const int o0 = blockIdx.x * BN;
    const int b0 = blockIdx.y * BM;
    const int k0 = blockIdx.z * KC;

    // ---- stage x[b0:b0+64][k0:k0+128] -> xs : 2048 float4, 8 per thread, coalesced
    #pragma unroll
    for (int r = 0; r < 8; ++r) {
        const int f4 = r * 256 + t;
        const int b  = f4 >> 5;          // 32 float4 per 128-float row
        const int q  = f4 & 31;
        const float4 v = *(const float4*)&x[(size_t)(b0 + b) * NIN + k0 + q * 4];
        *(float4*)&xs[b * XPAD + q * 4] = v;
    }
    // ---- stage wd = wp - wn over [k0:k0+128][o0:o0+32] : 1024 float4, 4 per thread
    #pragma unroll
    for (int r = 0; r < 4; ++r) {
        const int f4 = r * 256 + t;
        const int k  = f4 >> 3;          // 8 float4 per 32-float row
        const int q  = f4 & 7;
        const size_t g = (size_t)(k0 + k) * NOUT + o0 + q * 4;
        const float4 p = *(const float4*)&wp[g];
        const float4 n = *(const float4*)&wn[g];
        float4 d;
        d.x = p.x - n.x; d.y = p.y - n.y; d.z = p.z - n.z; d.w = p.w - n.w;
        *(float4*)&wd[k * BN + q * 4] = d;
    }
    __syncthreads();

    // micro-tile: 2 batch rows x 4 output cols per thread
    const int tx = t & 7;    // o-quad: o = o0 + tx*4 + j   (8 quads = 32 cols)
    const int ty = t >> 3;   // b-pair: b = b0 + ty*2 + i   (32 pairs = 64 rows)

    float acc[2][4] = {{0.f,0.f,0.f,0.f},{0.f,0.f,0.f,0.f}};

    const float* xr0 = &xs[(ty * 2 + 0) * XPAD];
    const float* xr1 = &xs[(ty * 2 + 1) * XPAD];
    const float* wr  = &wd[tx * 4];

    #pragma unroll 8
    for (int k = 0; k < KC; ++k) {
        const float4 w4 = *(const float4*)&wr[k * BN];   // ds_read_b128, dense
        const float x0 = xr0[k];                         // broadcast reads (8 addrs/wave)
        const float x1 = xr1[k];
        acc[0][0] += x0 * w4.x; acc[0][1] += x0 * w4.y;
        acc[0][2] += x0 * w4.z; acc[0][3] += x0 * w4.w;
        acc[1][0] += x1 * w4.x; acc[1][1] += x1 * w4.y;
        acc[1][2] += x1 * w4.z; acc[1][3] += x1 * w4.w;
    }

    // bias (added exactly once: only the k-chunk-0 blocks)
    float bias[4] = {0.f, 0.f, 0.f, 0.f};
    if (blockIdx.z == 0) {
        #pragma unroll
        for (int j = 0; j < 4; ++j) {
            const int o = o0 + tx * 4 + j;
            bias[j] = bp[o] - bn[o];
        }
    }

    // combine K-split partials with device-scope fp32 atomics (out memset to 0)
    #pragma unroll
    for (int i = 0; i < 2; ++i) {
        const int b = b0 + ty * 2 + i;
        #pragma unroll
        for (int j = 0; j < 4; ++j)
            atomicAdd(&out[(size_t)b * NOUT + o0 + tx * 4 + j], acc[i][j] + bias[j]);
    }
}

extern "C" void kernel_launch(void* const* d_in, const int* in_sizes, int n_in,
                              void* d_out, int out_size, void* d_ws, size_t ws_size,
                              hipStream_t stream)
{
    const float* x  = (const float*)d_in[0];
    const float* wp = (const float*)d_in[1];
    const float* wn = (const float*)d_in[2];
    const float* bp = (const float*)d_in[3];
    const float* bn = (const float*)d_in[4];
    float* out = (float*)d_out;

    // harness poisons d_out with 0xAA before every timed launch; atomics need zeros
    hipMemsetAsync(out, 0, (size_t)NB * NOUT * sizeof(float), stream);

    dim3 grid(NOUT / BN, NB / BM, NIN / KC);   // 32 x 2 x 8 = 512 blocks
    memr_fc<<<grid, 256, 0, stream>>>(x, wp, wn, bp, bn, out);
}

// Round 2
// 78.013 us; speedup vs baseline: 1.0958x; 1.0958x over previous
//
#include <hip/hip_runtime.h>

// y[b,o] = sum_i x[b,i] * (wp[i,o] - wn[i,o]) + (bp[o] - bn[o])
// (G_OFF / k_cond / K_V cancel exactly in the differential-pair readout)
//
// Structure: kernel 1 computes K-split partials into d_ws (no atomics, no
// memset needed); kernel 2 reduces 16 partials + bias into d_out.

#define NB   128
#define NIN  1024
#define NOUT 1024

#define OT   32              // output cols per block
#define KC   64              // k-chunk per block
#define NKS  (NIN / KC)      // 16 K-split slices
#define XP   65              // xs row stride (odd -> 2-way-max bank aliasing on x reads)

__global__ __launch_bounds__(128) void memr_partial(
    const float* __restrict__ x,  const float* __restrict__ wp,
    const float* __restrict__ wn, float* __restrict__ ws)
{
    __shared__ float xs[NB * XP];   // 33280 B : x[0:128][k0:k0+64], stride 65
    __shared__ float wd[KC * OT];   //  8192 B : (wp-wn)[k0:k0+64][o0:o0+32]

    const int t  = threadIdx.x;
    const int o0 = blockIdx.x * OT;
    const int ks = blockIdx.y;
    const int k0 = ks * KC;

    // ---- stage x: 2048 float4 coalesced loads, scalar LDS stores (odd stride)
    #pragma unroll
    for (int r = 0; r < 16; ++r) {
        const int f4 = r * 128 + t;
        const int b  = f4 >> 4;           // 16 float4 per 64-float row
        const int q  = f4 & 15;
        const float4 v = *(const float4*)&x[(size_t)b * NIN + k0 + q * 4];
        float* d = &xs[b * XP + q * 4];
        d[0] = v.x; d[1] = v.y; d[2] = v.z; d[3] = v.w;
    }
    // ---- stage wd = wp - wn : 512 float4 each, coalesced
    #pragma unroll
    for (int r = 0; r < 4; ++r) {
        const int f4 = r * 128 + t;
        const int k  = f4 >> 3;           // 8 float4 per 32-float row
        const int q  = f4 & 7;
        const size_t g = (size_t)(k0 + k) * NOUT + o0 + q * 4;
        const float4 p = *(const float4*)&wp[g];
        const float4 n = *(const float4*)&wn[g];
        float4 d4;
        d4.x = p.x - n.x; d4.y = p.y - n.y; d4.z = p.z - n.z; d4.w = p.w - n.w;
        *(float4*)&wd[k * OT + q * 4] = d4;
    }
    __syncthreads();

    // micro-tile: 8 batch rows x 4 output cols per thread (32 acc VGPRs)
    // per k per wave: 1 ds_read_b128 (w) + 8 ds_read_b32 (x broadcast, 2-way max)
    // feeding 32 FMAs/thread -> VALU-bound with ~4x LDS headroom
    const int tx = t & 7;    // o-quad: o = o0 + tx*4 + j
    const int ty = t >> 3;   // b-octet: b = ty*8 + i, ty in 0..15

    float acc[8][4];
    #pragma unroll
    for (int i = 0; i < 8; ++i)
        #pragma unroll
        for (int j = 0; j < 4; ++j) acc[i][j] = 0.f;

    const float* xr = &xs[ty * 8 * XP];
    const float* wr = &wd[tx * 4];

    #pragma unroll 4
    for (int k = 0; k < KC; ++k) {
        const float4 w4 = *(const float4*)&wr[k * OT];
        float xv[8];
        #pragma unroll
        for (int i = 0; i < 8; ++i) xv[i] = xr[i * XP + k];
        #pragma unroll
        for (int i = 0; i < 8; ++i) {
            acc[i][0] += xv[i] * w4.x;
            acc[i][1] += xv[i] * w4.y;
            acc[i][2] += xv[i] * w4.z;
            acc[i][3] += xv[i] * w4.w;
        }
    }

    // ---- store partial tile to ws[ks][b][o] (float4, coalesced)
    float* wsb = ws + (size_t)ks * NB * NOUT;
    #pragma unroll
    for (int i = 0; i < 8; ++i) {
        const int b = ty * 8 + i;
        float4 v;
        v.x = acc[i][0]; v.y = acc[i][1]; v.z = acc[i][2]; v.w = acc[i][3];
        *(float4*)&wsb[(size_t)b * NOUT + o0 + tx * 4] = v;
    }
}

__global__ __launch_bounds__(256) void memr_reduce(
    const float* __restrict__ ws, const float* __restrict__ bp,
    const float* __restrict__ bn, float* __restrict__ out)
{
    const int g = blockIdx.x * 256 + threadIdx.x;   // 0..131071 == b*1024+o
    const int o = g & (NOUT - 1);
    float s = bp[o] - bn[o];
    #pragma unroll
    for (int ks = 0; ks < NKS; ++ks)
        s += ws[(size_t)ks * NB * NOUT + g];
    out[g] = s;
}

extern "C" void kernel_launch(void* const* d_in, const int* in_sizes, int n_in,
                              void* d_out, int out_size, void* d_ws, size_t ws_size,
                              hipStream_t stream)
{
    const float* x  = (const float*)d_in[0];
    const float* wp = (const float*)d_in[1];
    const float* wn = (const float*)d_in[2];
    const float* bp = (const float*)d_in[3];
    const float* bn = (const float*)d_in[4];
    float* out = (float*)d_out;
    float* ws  = (float*)d_ws;     // needs 16*128*1024*4 = 8 MB (ws is ~256 MB)

    dim3 g1(NOUT / OT, NKS);       // 32 x 16 = 512 blocks, 2 per CU
    memr_partial<<<g1, 128, 0, stream>>>(x, wp, wn, ws);
    memr_reduce<<<NB * NOUT / 256, 256, 0, stream>>>(ws, bp, bn, out);
}